// Round 15
// baseline (559.776 us; speedup 1.0000x reference)
//
#include <hip/hip_runtime.h>

#define T_DIM 512
#define B_DIM 64
#define I_DIM 256
#define H_DIM 512
#define O_DIM 256

typedef __attribute__((ext_vector_type(8))) short short8;
typedef __attribute__((ext_vector_type(4))) float f32x4;
typedef __attribute__((ext_vector_type(4))) int   i32x4;

__device__ __forceinline__ unsigned short f2bf(float f){
  unsigned int u = __builtin_bit_cast(unsigned int, f);
  u += 0x7fffu + ((u >> 16) & 1u);
  return (unsigned short)(u >> 16);
}
__device__ __forceinline__ float bf2f(unsigned short b){
  unsigned int u = ((unsigned int)b) << 16;
  return __builtin_bit_cast(float, u);
}

#if defined(__has_builtin)
#if __has_builtin(__builtin_amdgcn_update_dpp)
#define HAVE_DPP 1
#endif
#endif

// ------- small pre-pass: bf16 pack (W_ih, W_out) + int8 quant (W_hh) -------
// Also zeroes the 128 progress flags (xprog[64] | prog[64]) each launch.
__global__ void pack_w(const float* __restrict__ wih,
                       const float* __restrict__ wout,
                       const float* __restrict__ whh,
                       unsigned short* __restrict__ wihb,
                       unsigned short* __restrict__ woutb,
                       int* __restrict__ Wq,
                       int* __restrict__ flags){
  const int NW = (H_DIM*I_DIM)/4;         // 32768 float4s each (wih, wout)
  int i = blockIdx.x * 256 + threadIdx.x; // grid covers 2*NW + 65536 exactly
  if (blockIdx.x == 0 && threadIdx.x < 128) flags[threadIdx.x] = 0;
  if (i < 2*NW){
    const float4* src; unsigned short* dst; int j;
    if (i < NW) { src = (const float4*)wih;  dst = wihb;  j = i; }
    else        { src = (const float4*)wout; dst = woutb; j = i - NW; }
    float4 f = src[j];
    ushort4 v;
    v.x = f2bf(f.x); v.y = f2bf(f.y); v.z = f2bf(f.z); v.w = f2bf(f.w);
    ((ushort4*)dst)[j] = v;
  } else {
    int p = i - 2*NW;                     // 65536 packs of 4
    const float s  = 0.04419417382415922f;
    const float qs = 127.0f / s;
    int out = 0;
    #pragma unroll
    for (int k = 0; k < 4; ++k){
      float w = whh[(size_t)p*4 + k];
      int q = __float2int_rn(w * qs);
      q = q < -127 ? -127 : (q > 127 ? 127 : q);
      out |= (q & 0xff) << (8*k);
    }
    Wq[p] = out;
  }
}

// ================== fully-fused pipeline: GEMM1 -> rnn -> GEMM2 ==================
// R15 = R14 (bit-exact verified) with ONE change: XCD-segregated role placement.
// R14 accounting: fused 457us = wait ~10 + rnn 512 x ~1955cyc (+13% vs solo 1731)
// + tail ~3. The +13% is L2 interference: rnn blocks shared every XCD's 4MB L2
// with ~24 streaming GEMM blocks (FETCH 17->68MB). Fix via the practical
// round-robin mapping xcd = blk&7 (perf-only assumption, G16-safe):
//   xcd 0-1: rnn   (64 blocks, 32/XCD = all CUs) -- owns two quiet L2s
//   xcd 2-3: GEMM1 (64 blocks), t-ordered rounds, publishes xprog[g]
//   xcd 4-7: GEMM2 (128 blocks), tile tau = k2+128*it, polls prog[]
// Sync machinery unchanged from R14: wave-wide RELAXED agent loads + s_sleep
// (no RMW storm), producer-side __hip_atomic_store RELEASE (wbl2, no inv),
// no consumer acquire fences. 256 blocks x 84KB LDS = 1/CU -> all co-resident,
// dispatch-order deadlock-free. All MFMA chains k0-ascending -> bit-identical.
__global__
__attribute__((amdgpu_flat_work_group_size(512, 512), amdgpu_waves_per_eu(2, 2)))
void fused_pipeline(
    const int* __restrict__ Wq,               // [512][512] int8, row-major
    const float* __restrict__ x,              // [T*B][I] fp32
    const unsigned short* __restrict__ wihb,  // [H][I] bf16
    const float* __restrict__ bih,
    const float* __restrict__ bhh,
    unsigned short* __restrict__ xp,          // [T*B][H] bf16 (intermediate)
    unsigned short* __restrict__ rnn,         // [T*B][H] bf16 (intermediate)
    float* __restrict__ hlast,                // [B*H] fp32 (second output)
    const unsigned short* __restrict__ wob,   // [O][H] bf16
    const float* __restrict__ bout,           // [O]
    float* __restrict__ y,                    // [T*B][O] fp32 (first output)
    int* __restrict__ xprog,                  // [64] GEMM1 progress
    int* __restrict__ prog)                   // [64] rnn progress
{
  __shared__ union {
    char H[2][512];                           // rnn: int8 h, double-buffered
    struct { unsigned short As[128][40]; unsigned short Bs[128][40]; } g;
    char occupancy_cap[84 * 1024];            // 1 block/CU in compiler model
  } sm;
  const int blk  = blockIdx.x;
  const int xcd  = blk & 7;                   // practical round-robin XCD id
  const int idx  = blk >> 3;                  // 0..31 within XCD
  const int tid  = threadIdx.x;               // 0..511
  const int lane = tid & 63;

  if (xcd >= 2 && xcd < 4){
    // ======================= GEMM1 role (producer, XCD 2-3) =======================
    const int g   = idx*2 + (xcd - 2);        // 0..63
    const int wid = tid >> 6;
    const int wm  = wid >> 2, wn = wid & 3;   // 2x4 waves: 64x32 per wave
    const int lr  = lane & 15, lq = lane >> 4;
    const int sr  = tid >> 2, so = tid & 3;

    for (int r = 0; r < 4; ++r){
      const int m0 = (g + 64*r) * 128;        // rounds in t-order across blocks
      for (int nt = 0; nt < 4; ++nt){
        const int n0 = nt * 128;
        f32x4 acc[4][2];
        #pragma unroll
        for (int i = 0; i < 4; ++i)
          #pragma unroll
          for (int j = 0; j < 2; ++j) acc[i][j] = (f32x4){0.f, 0.f, 0.f, 0.f};

        for (int k0 = 0; k0 < I_DIM; k0 += 32){
          {
            const float* srcp = x + (size_t)(m0 + sr)*I_DIM + k0 + so*8;
            float4 q0 = *(const float4*)srcp;
            float4 q1 = *(const float4*)(srcp + 4);
            uint4 v;
            v.x = (unsigned)f2bf(q0.x) | ((unsigned)f2bf(q0.y) << 16);
            v.y = (unsigned)f2bf(q0.z) | ((unsigned)f2bf(q0.w) << 16);
            v.z = (unsigned)f2bf(q1.x) | ((unsigned)f2bf(q1.y) << 16);
            v.w = (unsigned)f2bf(q1.z) | ((unsigned)f2bf(q1.w) << 16);
            *(uint4*)&sm.g.As[sr][so*8] = v;
          }
          *(uint4*)&sm.g.Bs[sr][so*8] = *(const uint4*)(wihb + (size_t)(n0 + sr)*I_DIM + k0 + so*8);
          __syncthreads();
          short8 a[4], bw[2];
          #pragma unroll
          for (int i = 0; i < 4; ++i)
            a[i]  = __builtin_bit_cast(short8, *(const uint4*)&sm.g.As[wm*64 + i*16 + lr][lq*8]);
          #pragma unroll
          for (int j = 0; j < 2; ++j)
            bw[j] = __builtin_bit_cast(short8, *(const uint4*)&sm.g.Bs[wn*32 + j*16 + lr][lq*8]);
          #pragma unroll
          for (int i = 0; i < 4; ++i)
            #pragma unroll
            for (int j = 0; j < 2; ++j)
              acc[i][j] = __builtin_amdgcn_mfma_f32_16x16x32_bf16(a[i], bw[j], acc[i][j], 0, 0, 0);
          __syncthreads();
        }
        #pragma unroll
        for (int i = 0; i < 4; ++i)
          #pragma unroll
          for (int j = 0; j < 2; ++j)
            #pragma unroll
            for (int rr = 0; rr < 4; ++rr){
              int grow = m0 + wm*64 + i*16 + lq*4 + rr;
              int gcol = n0 + wn*32 + j*16 + lr;
              xp[(size_t)grow*H_DIM + gcol] = f2bf(acc[i][j][rr] + bih[gcol] + bhh[gcol]);
            }
      }
      __syncthreads();                        // drains vmcnt: round's stores done
      if (tid == 0)
        __hip_atomic_store(&xprog[g], r + 1, __ATOMIC_RELEASE, __HIP_MEMORY_SCOPE_AGENT);
    }

  } else if (xcd < 2){
    // ======================= rnn role (XCD 0-1; R12-verbatim compute) =======================
    const int b    = idx*2 + xcd;             // 0..63
    const int wv   = tid >> 6;                // wave: rows [64wv, 64wv+64)
    const int lr   = lane & 15;
    const int hi   = lane >> 4;
    const int rloc = 16*((lane >> 2) & 3) + 4*(lane >> 4) + (lane & 3);
    const int row  = 64*wv + rloc;

    i32x4 wf[4][8];
    const char* Wb = (const char*)Wq;
    #pragma unroll
    for (int rt = 0; rt < 4; ++rt){
      const char* rowp = Wb + (size_t)(64*wv + 16*rt + lr)*512 + hi*16;
      #pragma unroll
      for (int kt = 0; kt < 8; ++kt)
        wf[rt][kt] = *(const i32x4*)(rowp + (size_t)kt*64);
    }

    if (tid < 256) ((int*)sm.H)[tid] = 0;     // zero both h buffers (1 KB)
    // wait for xp rows t<128 (round 1 from every GEMM1 block)
    if (tid < 64)
      while (__hip_atomic_load(&xprog[tid], __ATOMIC_RELAXED, __HIP_MEMORY_SCOPE_AGENT) < 1)
        __builtin_amdgcn_s_sleep(8);
    __syncthreads();

    const float kscale2 = 2.0f * 0.04419417382415922f / (127.0f * 127.0f);
    const int BH = B_DIM * H_DIM;

    float xp2_next = 2.0f * bf2f(xp[(size_t)b*H_DIM + row]);   // t = 0 prefetch
    float h = 0.0f;

    for (int t = 0; t < T_DIM; ++t){
      if (t && (t & 31) == 0){
        int hh = 32*(t >> 5) + 33; if (hh > 512) hh = 512;
        int needk = (hh + 127) >> 7;
        if (tid < 64)
          while (__hip_atomic_load(&xprog[tid], __ATOMIC_RELAXED, __HIP_MEMORY_SCOPE_AGENT) < needk)
            __builtin_amdgcn_s_sleep(8);
        __syncthreads();
      }
      float xp2_cur = xp2_next;
      {
        int tn = (t + 1 < T_DIM) ? (t + 1) : t;
        xp2_next = 2.0f * bf2f(xp[(size_t)tn*BH + (size_t)b*H_DIM + row]);
      }

      const char* Hc = sm.H[t & 1];
      i32x4 bf0 = *(const i32x4*)(Hc + 0*64 + hi*16);
      i32x4 bf1 = *(const i32x4*)(Hc + 1*64 + hi*16);
      i32x4 bf2 = *(const i32x4*)(Hc + 2*64 + hi*16);
      i32x4 bf3 = *(const i32x4*)(Hc + 3*64 + hi*16);
      i32x4 bf4 = *(const i32x4*)(Hc + 4*64 + hi*16);
      i32x4 bf5 = *(const i32x4*)(Hc + 5*64 + hi*16);
      i32x4 bf6 = *(const i32x4*)(Hc + 6*64 + hi*16);
      i32x4 bf7 = *(const i32x4*)(Hc + 7*64 + hi*16);

      i32x4 a0 = {0,0,0,0}, a1 = {0,0,0,0}, a2 = {0,0,0,0}, a3 = {0,0,0,0};
      a0 = __builtin_amdgcn_mfma_i32_16x16x64_i8(wf[0][0], bf0, a0, 0, 0, 0);
      a1 = __builtin_amdgcn_mfma_i32_16x16x64_i8(wf[1][0], bf0, a1, 0, 0, 0);
      a2 = __builtin_amdgcn_mfma_i32_16x16x64_i8(wf[2][0], bf0, a2, 0, 0, 0);
      a3 = __builtin_amdgcn_mfma_i32_16x16x64_i8(wf[3][0], bf0, a3, 0, 0, 0);
      a0 = __builtin_amdgcn_mfma_i32_16x16x64_i8(wf[0][1], bf1, a0, 0, 0, 0);
      a1 = __builtin_amdgcn_mfma_i32_16x16x64_i8(wf[1][1], bf1, a1, 0, 0, 0);
      a2 = __builtin_amdgcn_mfma_i32_16x16x64_i8(wf[2][1], bf1, a2, 0, 0, 0);
      a3 = __builtin_amdgcn_mfma_i32_16x16x64_i8(wf[3][1], bf1, a3, 0, 0, 0);
      a0 = __builtin_amdgcn_mfma_i32_16x16x64_i8(wf[0][2], bf2, a0, 0, 0, 0);
      a1 = __builtin_amdgcn_mfma_i32_16x16x64_i8(wf[1][2], bf2, a1, 0, 0, 0);
      a2 = __builtin_amdgcn_mfma_i32_16x16x64_i8(wf[2][2], bf2, a2, 0, 0, 0);
      a3 = __builtin_amdgcn_mfma_i32_16x16x64_i8(wf[3][2], bf2, a3, 0, 0, 0);
      a0 = __builtin_amdgcn_mfma_i32_16x16x64_i8(wf[0][3], bf3, a0, 0, 0, 0);
      a1 = __builtin_amdgcn_mfma_i32_16x16x64_i8(wf[1][3], bf3, a1, 0, 0, 0);
      a2 = __builtin_amdgcn_mfma_i32_16x16x64_i8(wf[2][3], bf3, a2, 0, 0, 0);
      a3 = __builtin_amdgcn_mfma_i32_16x16x64_i8(wf[3][3], bf3, a3, 0, 0, 0);
      a0 = __builtin_amdgcn_mfma_i32_16x16x64_i8(wf[0][4], bf4, a0, 0, 0, 0);
      a1 = __builtin_amdgcn_mfma_i32_16x16x64_i8(wf[1][4], bf4, a1, 0, 0, 0);
      a2 = __builtin_amdgcn_mfma_i32_16x16x64_i8(wf[2][4], bf4, a2, 0, 0, 0);
      a3 = __builtin_amdgcn_mfma_i32_16x16x64_i8(wf[3][4], bf4, a3, 0, 0, 0);
      a0 = __builtin_amdgcn_mfma_i32_16x16x64_i8(wf[0][5], bf5, a0, 0, 0, 0);
      a1 = __builtin_amdgcn_mfma_i32_16x16x64_i8(wf[1][5], bf5, a1, 0, 0, 0);
      a2 = __builtin_amdgcn_mfma_i32_16x16x64_i8(wf[2][5], bf5, a2, 0, 0, 0);
      a3 = __builtin_amdgcn_mfma_i32_16x16x64_i8(wf[3][5], bf5, a3, 0, 0, 0);
      a0 = __builtin_amdgcn_mfma_i32_16x16x64_i8(wf[0][6], bf6, a0, 0, 0, 0);
      a1 = __builtin_amdgcn_mfma_i32_16x16x64_i8(wf[1][6], bf6, a1, 0, 0, 0);
      a2 = __builtin_amdgcn_mfma_i32_16x16x64_i8(wf[2][6], bf6, a2, 0, 0, 0);
      a3 = __builtin_amdgcn_mfma_i32_16x16x64_i8(wf[3][6], bf6, a3, 0, 0, 0);
      a0 = __builtin_amdgcn_mfma_i32_16x16x64_i8(wf[0][7], bf7, a0, 0, 0, 0);
      a1 = __builtin_amdgcn_mfma_i32_16x16x64_i8(wf[1][7], bf7, a1, 0, 0, 0);
      a2 = __builtin_amdgcn_mfma_i32_16x16x64_i8(wf[2][7], bf7, a2, 0, 0, 0);
      a3 = __builtin_amdgcn_mfma_i32_16x16x64_i8(wf[3][7], bf7, a3, 0, 0, 0);

      int f0, f1, f2, f3;
      {
        int e0 = (lane & 4) ? a1[0] : a0[0];
        int e1 = (lane & 4) ? a3[0] : a2[0];
        f0 = (lane & 8) ? e1 : e0;
        e0 = (lane & 4) ? a1[1] : a0[1];
        e1 = (lane & 4) ? a3[1] : a2[1];
        f1 = (lane & 8) ? e1 : e0;
        e0 = (lane & 4) ? a1[2] : a0[2];
        e1 = (lane & 4) ? a3[2] : a2[2];
        f2 = (lane & 8) ? e1 : e0;
        e0 = (lane & 4) ? a1[3] : a0[3];
        e1 = (lane & 4) ? a3[3] : a2[3];
        f3 = (lane & 8) ? e1 : e0;
      }
      int g0 = (lane & 1) ? f1 : f0;
      int g1 = (lane & 1) ? f3 : f2;
      int am = (lane & 2) ? g1 : g0;          // no shfl: ownership IS the permutation

      float pre2 = xp2_cur + (float)am * kscale2;      // = 2x
      float e2 = __expf(pre2);
      float rc = __builtin_amdgcn_rcpf(e2 + 1.0f);
      h = fmaf(-2.0f, rc, 1.0f);

      int q = __float2int_rn(h * 127.0f) & 0xff;
#ifdef HAVE_DPP
      int p1 = __builtin_amdgcn_update_dpp(0, q, 0xB1, 0xf, 0xf, true);
      int yb = q | (p1 << 8);
      int p2 = __builtin_amdgcn_update_dpp(0, yb, 0x4E, 0xf, 0xf, true);
      int z  = yb | (p2 << 16);
      if ((lane & 3) == 0) ((int*)sm.H[(t + 1) & 1])[row >> 2] = z;
#else
      sm.H[(t + 1) & 1][row] = (char)q;
#endif
      asm volatile("s_waitcnt lgkmcnt(0)" ::: "memory");
      __builtin_amdgcn_s_barrier();

      rnn[(size_t)t*BH + (size_t)b*H_DIM + row] = f2bf(h);

      if ((t & 31) == 31){
        __syncthreads();                      // drains vmcnt: stores <= t done
        if (tid == 0)
          __hip_atomic_store(&prog[b], t + 1, __ATOMIC_RELEASE, __HIP_MEMORY_SCOPE_AGENT);
      }
    }
    hlast[(size_t)b*H_DIM + row] = h;

  } else {
    // ======================= GEMM2 role (consumer, XCD 4-7) =======================
    const int k2  = idx*4 + (xcd - 4);        // 0..127
    const int wid = tid >> 6;
    const int wm  = wid >> 2, wn = wid & 3;   // 2x4 waves: 64x32 per wave
    const int lr  = lane & 15, lq = lane >> 4;
    const int sr  = tid >> 2, so = tid & 3;

    for (int it = 0; it < 4; ++it){
      const int tau = k2 + 128*it;            // ascending mt per block; final 8
      const int mt  = tau >> 1;               // tiles on 8 distinct blocks
      const int n0  = (tau & 1) * 128;
      const int m0  = mt * 128;
      const int need = 2*mt + 2;
      if (tid < 64)
        while (__hip_atomic_load(&prog[tid], __ATOMIC_RELAXED, __HIP_MEMORY_SCOPE_AGENT) < need)
          __builtin_amdgcn_s_sleep(32);
      __syncthreads();

      f32x4 acc[4][2];
      #pragma unroll
      for (int i = 0; i < 4; ++i)
        #pragma unroll
        for (int j = 0; j < 2; ++j) acc[i][j] = (f32x4){0.f, 0.f, 0.f, 0.f};

      for (int k0 = 0; k0 < H_DIM; k0 += 32){
        *(uint4*)&sm.g.As[sr][so*8] = *(const uint4*)(rnn + (size_t)(m0 + sr)*H_DIM + k0 + so*8);
        *(uint4*)&sm.g.Bs[sr][so*8] = *(const uint4*)(wob + (size_t)(n0 + sr)*H_DIM + k0 + so*8);
        __syncthreads();
        short8 a[4], bw[2];
        #pragma unroll
        for (int i = 0; i < 4; ++i)
          a[i]  = __builtin_bit_cast(short8, *(const uint4*)&sm.g.As[wm*64 + i*16 + lr][lq*8]);
        #pragma unroll
        for (int j = 0; j < 2; ++j)
          bw[j] = __builtin_bit_cast(short8, *(const uint4*)&sm.g.Bs[wn*32 + j*16 + lr][lq*8]);
        #pragma unroll
        for (int i = 0; i < 4; ++i)
          #pragma unroll
          for (int j = 0; j < 2; ++j)
            acc[i][j] = __builtin_amdgcn_mfma_f32_16x16x32_bf16(a[i], bw[j], acc[i][j], 0, 0, 0);
        __syncthreads();
      }

      #pragma unroll
      for (int i = 0; i < 4; ++i)
        #pragma unroll
        for (int j = 0; j < 2; ++j)
          #pragma unroll
          for (int rr = 0; rr < 4; ++rr){
            int grow = m0 + wm*64 + i*16 + lq*4 + rr;
            int gcol = n0 + wn*32 + j*16 + lr;
            y[(size_t)grow*O_DIM + gcol] = acc[i][j][rr] + bout[gcol];
          }
    }
  }
}

extern "C" void kernel_launch(void* const* d_in, const int* in_sizes, int n_in,
                              void* d_out, int out_size, void* d_ws, size_t ws_size,
                              hipStream_t stream){
  (void)in_sizes; (void)n_in; (void)out_size; (void)ws_size;
  const float* x    = (const float*)d_in[0];
  const float* Wih  = (const float*)d_in[1];
  const float* Whh  = (const float*)d_in[2];
  const float* bih  = (const float*)d_in[3];
  const float* bhh  = (const float*)d_in[4];
  const float* Wout = (const float*)d_in[5];
  const float* bout = (const float*)d_in[6];
  float* y     = (float*)d_out;
  float* hlast = y + (size_t)T_DIM * B_DIM * O_DIM;

  char* ws = (char*)d_ws;
  const size_t MB = 1024*1024;
  unsigned short* xp   = (unsigned short*)ws;                      // 32 MB
  unsigned short* rnn  = (unsigned short*)(ws + 32*MB);            // 32 MB
  int*            Wq   = (int*)           (ws + 64*MB);            // 256 KB
  unsigned short* wob  = (unsigned short*)(ws + 64*MB + 256*1024); // 256 KB
  unsigned short* wihb = (unsigned short*)(ws + 64*MB + 512*1024); // 256 KB
  int*            flags= (int*)           (ws + 66*MB);            // 512 B
  int*            xprog= flags;                                    // [64]
  int*            prog = flags + 64;                               // [64]

  // pack W_ih/W_out + quant W_hh (+ zero flags): 131072 = 512*256 threads
  pack_w<<<512, 256, 0, stream>>>(Wih, Wout, Whh, wihb, wob, Wq, flags);
  fused_pipeline<<<256, 512, 0, stream>>>(
      Wq, x, wihb, bih, bhh, xp, rnn, hlast, wob, bout, y, xprog, prog);
}

// Round 16
// 497.238 us; speedup vs baseline: 1.1258x; 1.1258x over previous
//
#include <hip/hip_runtime.h>

#define T_DIM 512
#define B_DIM 64
#define I_DIM 256
#define H_DIM 512
#define O_DIM 256

typedef __attribute__((ext_vector_type(8))) short short8;
typedef __attribute__((ext_vector_type(4))) float f32x4;
typedef __attribute__((ext_vector_type(4))) int   i32x4;

__device__ __forceinline__ unsigned short f2bf(float f){
  unsigned int u = __builtin_bit_cast(unsigned int, f);
  u += 0x7fffu + ((u >> 16) & 1u);
  return (unsigned short)(u >> 16);
}
__device__ __forceinline__ float bf2f(unsigned short b){
  unsigned int u = ((unsigned int)b) << 16;
  return __builtin_bit_cast(float, u);
}

#if defined(__has_builtin)
#if __has_builtin(__builtin_amdgcn_update_dpp)
#define HAVE_DPP 1
#endif
#endif

// ------- small pre-pass: bf16 pack (W_ih, W_out) + int8 quant (W_hh) -------
// x is not staged -- GEMM1 converts in-tile (same f2bf rounding, bit-identical).
__global__ void pack_w(const float* __restrict__ wih,
                       const float* __restrict__ wout,
                       const float* __restrict__ whh,
                       unsigned short* __restrict__ wihb,
                       unsigned short* __restrict__ woutb,
                       int* __restrict__ Wq){
  const int NW = (H_DIM*I_DIM)/4;         // 32768 float4s each (wih, wout)
  int i = blockIdx.x * 256 + threadIdx.x; // grid covers 2*NW + 65536 exactly
  if (i < 2*NW){
    const float4* src; unsigned short* dst; int j;
    if (i < NW) { src = (const float4*)wih;  dst = wihb;  j = i; }
    else        { src = (const float4*)wout; dst = woutb; j = i - NW; }
    float4 f = src[j];
    ushort4 v;
    v.x = f2bf(f.x); v.y = f2bf(f.y); v.z = f2bf(f.z); v.w = f2bf(f.w);
    ((ushort4*)dst)[j] = v;
  } else {
    int p = i - 2*NW;                     // 65536 packs of 4
    const float s  = 0.04419417382415922f;
    const float qs = 127.0f / s;
    int out = 0;
    #pragma unroll
    for (int k = 0; k < 4; ++k){
      float w = whh[(size_t)p*4 + k];
      int q = __float2int_rn(w * qs);
      q = q < -127 ? -127 : (q > 127 ? 127 : q);
      out |= (q & 0xff) << (8*k);
    }
    Wq[p] = out;
  }
}

// ---------------- recurrence (all-MFMA, shfl-free tail) ----------------
// Final form (session optimum, R12): step 1731 cyc = matrix 1306 (hard floor:
// 256 forced MFMA/CU/step; batch-in-B-cols trades CUs 1:1; cross-CU row-split
// sync >= savings; fusion arc R13-R15 measured net-negative) + ~300 LDS/pipe
// fill + ~125 tail/barrier (bounded by R8/R10/R11 results).
__global__
__attribute__((amdgpu_flat_work_group_size(512, 512), amdgpu_waves_per_eu(2, 2)))
void rnn_recur(
    const int* __restrict__ Wq,               // [512][512] int8, row-major
    const unsigned short* __restrict__ xp,    // [T*B*H] bf16
    unsigned short* __restrict__ rnn,         // [T*B*H] bf16
    float* __restrict__ hlast)                // [B*H] fp32 (second output)
{
  __shared__ union {
    char H[2][512];                           // int8 h, double-buffered, linear
    char occupancy_cap[84 * 1024];            // forces 1 WG/CU in compiler model
  } sm;
  const int b    = blockIdx.x;
  const int tid  = threadIdx.x;               // 0..511
  const int lane = tid & 63;
  const int wv   = tid >> 6;                  // wave: rows [64wv, 64wv+64)
  const int lr   = lane & 15;                 // A row within tile
  const int hi   = lane >> 4;                 // k-block (16 bytes each)

  // row this thread finalizes = its own cndmask-selected D element:
  // rloc = 16*rt + 4*hi + r with rt=(lane>>2)&3, r=lane&3. row%4==0 <=> lane%4==0.
  const int rloc = 16*((lane >> 2) & 3) + 4*(lane >> 4) + (lane & 3);
  const int row  = 64*wv + rloc;

  // A-fragments: 4 row-tiles x 8 K-steps x 16B = 128 regs (AGPR-resident OK)
  i32x4 wf[4][8];
  const char* Wb = (const char*)Wq;
  #pragma unroll
  for (int rt = 0; rt < 4; ++rt){
    const char* rowp = Wb + (size_t)(64*wv + 16*rt + lr)*512 + hi*16;
    #pragma unroll
    for (int kt = 0; kt < 8; ++kt)
      wf[rt][kt] = *(const i32x4*)(rowp + (size_t)kt*64);
  }

  if (tid < 256) ((int*)sm.H)[tid] = 0;       // zero both h buffers (1 KB)

  const float kscale2 = 2.0f * 0.04419417382415922f / (127.0f * 127.0f);
  const int BH = B_DIM * H_DIM;

  float xp2_next = 2.0f * bf2f(xp[(size_t)b*H_DIM + row]);   // t = 0 prefetch
  float h = 0.0f;
  __syncthreads();

  for (int t = 0; t < T_DIM; ++t){
    float xp2_cur = xp2_next;
    {
      int tn = (t + 1 < T_DIM) ? (t + 1) : t;
      xp2_next = 2.0f * bf2f(xp[(size_t)tn*BH + (size_t)b*H_DIM + row]);
    }

    const char* Hc = sm.H[t & 1];
    // hoist ALL B-fragment reads: 8 back-to-back ds_read_b128 (one latency
    // exposure), then the MFMA block consumes them with counted lgkm waits.
    i32x4 bf0 = *(const i32x4*)(Hc + 0*64 + hi*16);
    i32x4 bf1 = *(const i32x4*)(Hc + 1*64 + hi*16);
    i32x4 bf2 = *(const i32x4*)(Hc + 2*64 + hi*16);
    i32x4 bf3 = *(const i32x4*)(Hc + 3*64 + hi*16);
    i32x4 bf4 = *(const i32x4*)(Hc + 4*64 + hi*16);
    i32x4 bf5 = *(const i32x4*)(Hc + 5*64 + hi*16);
    i32x4 bf6 = *(const i32x4*)(Hc + 6*64 + hi*16);
    i32x4 bf7 = *(const i32x4*)(Hc + 7*64 + hi*16);

    i32x4 a0 = {0,0,0,0}, a1 = {0,0,0,0}, a2 = {0,0,0,0}, a3 = {0,0,0,0};
    a0 = __builtin_amdgcn_mfma_i32_16x16x64_i8(wf[0][0], bf0, a0, 0, 0, 0);
    a1 = __builtin_amdgcn_mfma_i32_16x16x64_i8(wf[1][0], bf0, a1, 0, 0, 0);
    a2 = __builtin_amdgcn_mfma_i32_16x16x64_i8(wf[2][0], bf0, a2, 0, 0, 0);
    a3 = __builtin_amdgcn_mfma_i32_16x16x64_i8(wf[3][0], bf0, a3, 0, 0, 0);
    a0 = __builtin_amdgcn_mfma_i32_16x16x64_i8(wf[0][1], bf1, a0, 0, 0, 0);
    a1 = __builtin_amdgcn_mfma_i32_16x16x64_i8(wf[1][1], bf1, a1, 0, 0, 0);
    a2 = __builtin_amdgcn_mfma_i32_16x16x64_i8(wf[2][1], bf1, a2, 0, 0, 0);
    a3 = __builtin_amdgcn_mfma_i32_16x16x64_i8(wf[3][1], bf1, a3, 0, 0, 0);
    a0 = __builtin_amdgcn_mfma_i32_16x16x64_i8(wf[0][2], bf2, a0, 0, 0, 0);
    a1 = __builtin_amdgcn_mfma_i32_16x16x64_i8(wf[1][2], bf2, a1, 0, 0, 0);
    a2 = __builtin_amdgcn_mfma_i32_16x16x64_i8(wf[2][2], bf2, a2, 0, 0, 0);
    a3 = __builtin_amdgcn_mfma_i32_16x16x64_i8(wf[3][2], bf2, a3, 0, 0, 0);
    a0 = __builtin_amdgcn_mfma_i32_16x16x64_i8(wf[0][3], bf3, a0, 0, 0, 0);
    a1 = __builtin_amdgcn_mfma_i32_16x16x64_i8(wf[1][3], bf3, a1, 0, 0, 0);
    a2 = __builtin_amdgcn_mfma_i32_16x16x64_i8(wf[2][3], bf3, a2, 0, 0, 0);
    a3 = __builtin_amdgcn_mfma_i32_16x16x64_i8(wf[3][3], bf3, a3, 0, 0, 0);
    a0 = __builtin_amdgcn_mfma_i32_16x16x64_i8(wf[0][4], bf4, a0, 0, 0, 0);
    a1 = __builtin_amdgcn_mfma_i32_16x16x64_i8(wf[1][4], bf4, a1, 0, 0, 0);
    a2 = __builtin_amdgcn_mfma_i32_16x16x64_i8(wf[2][4], bf4, a2, 0, 0, 0);
    a3 = __builtin_amdgcn_mfma_i32_16x16x64_i8(wf[3][4], bf4, a3, 0, 0, 0);
    a0 = __builtin_amdgcn_mfma_i32_16x16x64_i8(wf[0][5], bf5, a0, 0, 0, 0);
    a1 = __builtin_amdgcn_mfma_i32_16x16x64_i8(wf[1][5], bf5, a1, 0, 0, 0);
    a2 = __builtin_amdgcn_mfma_i32_16x16x64_i8(wf[2][5], bf5, a2, 0, 0, 0);
    a3 = __builtin_amdgcn_mfma_i32_16x16x64_i8(wf[3][5], bf5, a3, 0, 0, 0);
    a0 = __builtin_amdgcn_mfma_i32_16x16x64_i8(wf[0][6], bf6, a0, 0, 0, 0);
    a1 = __builtin_amdgcn_mfma_i32_16x16x64_i8(wf[1][6], bf6, a1, 0, 0, 0);
    a2 = __builtin_amdgcn_mfma_i32_16x16x64_i8(wf[2][6], bf6, a2, 0, 0, 0);
    a3 = __builtin_amdgcn_mfma_i32_16x16x64_i8(wf[3][6], bf6, a3, 0, 0, 0);
    a0 = __builtin_amdgcn_mfma_i32_16x16x64_i8(wf[0][7], bf7, a0, 0, 0, 0);
    a1 = __builtin_amdgcn_mfma_i32_16x16x64_i8(wf[1][7], bf7, a1, 0, 0, 0);
    a2 = __builtin_amdgcn_mfma_i32_16x16x64_i8(wf[2][7], bf7, a2, 0, 0, 0);
    a3 = __builtin_amdgcn_mfma_i32_16x16x64_i8(wf[3][7], bf7, a3, 0, 0, 0);

    // select own D element: rt=(lane>>2)&3 (among a0..a3), r=lane&3 (among regs)
    int f0, f1, f2, f3;
    {
      int e0 = (lane & 4) ? a1[0] : a0[0];
      int e1 = (lane & 4) ? a3[0] : a2[0];
      f0 = (lane & 8) ? e1 : e0;
      e0 = (lane & 4) ? a1[1] : a0[1];
      e1 = (lane & 4) ? a3[1] : a2[1];
      f1 = (lane & 8) ? e1 : e0;
      e0 = (lane & 4) ? a1[2] : a0[2];
      e1 = (lane & 4) ? a3[2] : a2[2];
      f2 = (lane & 8) ? e1 : e0;
      e0 = (lane & 4) ? a1[3] : a0[3];
      e1 = (lane & 4) ? a3[3] : a2[3];
      f3 = (lane & 8) ? e1 : e0;
    }
    int g0 = (lane & 1) ? f1 : f0;
    int g1 = (lane & 1) ? f3 : f2;
    int am = (lane & 2) ? g1 : g0;            // no shfl: ownership IS the permutation

    // tanh via 1 - 2/(e^{2x}+1): exact at extremes, no abs/copysign
    float pre2 = xp2_cur + (float)am * kscale2;      // = 2x
    float e2 = __expf(pre2);
    float rc = __builtin_amdgcn_rcpf(e2 + 1.0f);
    h = fmaf(-2.0f, rc, 1.0f);

    int q = __float2int_rn(h * 127.0f) & 0xff;
#ifdef HAVE_DPP
    // quad byte-pack: quad lanes own consecutive rows; leader (lane%4==0,
    // row%4==0) writes dword H[row>>2] of the next buffer. [R9-verified]
    int p1 = __builtin_amdgcn_update_dpp(0, q, 0xB1, 0xf, 0xf, true);   // byte from lane^1
    int y  = q | (p1 << 8);
    int p2 = __builtin_amdgcn_update_dpp(0, y, 0x4E, 0xf, 0xf, true);   // 2 bytes from lane^2
    int z  = y | (p2 << 16);
    if ((lane & 3) == 0) ((int*)sm.H[(t + 1) & 1])[row >> 2] = z;
#else
    sm.H[(t + 1) & 1][row] = (char)q;
#endif
    // raw barrier: fence only the LDS h-handoff (R8-validated)
    asm volatile("s_waitcnt lgkmcnt(0)" ::: "memory");
    __builtin_amdgcn_s_barrier();

    // rnn store AFTER the barrier: off the serial chain, retires under the
    // next step's MFMA phase (value-neutral reorder)
    rnn[(size_t)t*BH + (size_t)b*H_DIM + row] = f2bf(h);
  }
  hlast[(size_t)b*H_DIM + row] = h;
}

// ------- bf16 MFMA GEMM, 128x128 tile: C[M][N] = A[M][K]*B[N][K]^T + bias -------
// 4 waves, 64x64 per wave, acc[4][4], 16 MFMA/K-step. TA=float converts
// in-tile with the same f2bf rounding -> output values identical to staged.
// Grid: x = n-blocks (fast) so consecutive blocks share the A row panel (L2).
template<typename TA, typename TO>
__global__ __launch_bounds__(256) void gemm_bt128(
    const TA* __restrict__ A, const unsigned short* __restrict__ B,
    TO* __restrict__ C,
    const float* __restrict__ bias1, const float* __restrict__ bias2,
    int M, int N, int K)
{
  __shared__ unsigned short As[128][40];   // +8 pad breaks power-of-2 bank stride
  __shared__ unsigned short Bs[128][40];
  const int tid  = threadIdx.x;            // 256 threads = 4 waves (2x2)
  const int lane = tid & 63, wid = tid >> 6;
  const int m0   = blockIdx.y * 128;
  const int n0   = blockIdx.x * 128;
  const int wm   = wid >> 1, wn = wid & 1;
  const int lr   = lane & 15, lq = lane >> 4;
  const int sr0  = tid >> 2, so = tid & 3; // staging: row sr0/sr1, octet so
  const int sr1  = 64 + sr0;

  f32x4 acc[4][4];
  #pragma unroll
  for (int i = 0; i < 4; ++i)
    #pragma unroll
    for (int j = 0; j < 4; ++j) acc[i][j] = (f32x4){0.f, 0.f, 0.f, 0.f};

  for (int k0 = 0; k0 < K; k0 += 32){
    #pragma unroll
    for (int half = 0; half < 2; ++half){
      int sr = half ? sr1 : sr0;
      const TA* src = A + (size_t)(m0 + sr)*K + k0 + so*8;
      uint4 v;
      if constexpr (__is_same(TA, float)){
        float4 q0 = *(const float4*)src;
        float4 q1 = *(const float4*)(src + 4);
        v.x = (unsigned)f2bf(q0.x) | ((unsigned)f2bf(q0.y) << 16);
        v.y = (unsigned)f2bf(q0.z) | ((unsigned)f2bf(q0.w) << 16);
        v.z = (unsigned)f2bf(q1.x) | ((unsigned)f2bf(q1.y) << 16);
        v.w = (unsigned)f2bf(q1.z) | ((unsigned)f2bf(q1.w) << 16);
      } else {
        v = *(const uint4*)src;
      }
      *(uint4*)&As[sr][so*8] = v;
    }
    *(uint4*)&Bs[sr0][so*8] = *(const uint4*)(B + (size_t)(n0 + sr0)*K + k0 + so*8);
    *(uint4*)&Bs[sr1][so*8] = *(const uint4*)(B + (size_t)(n0 + sr1)*K + k0 + so*8);
    __syncthreads();
    short8 a[4], bfr[4];
    #pragma unroll
    for (int i = 0; i < 4; ++i){
      a[i]   = __builtin_bit_cast(short8, *(const uint4*)&As[wm*64 + i*16 + lr][lq*8]);
      bfr[i] = __builtin_bit_cast(short8, *(const uint4*)&Bs[wn*64 + i*16 + lr][lq*8]);
    }
    #pragma unroll
    for (int i = 0; i < 4; ++i)
      #pragma unroll
      for (int j = 0; j < 4; ++j)
        acc[i][j] = __builtin_amdgcn_mfma_f32_16x16x32_bf16(a[i], bfr[j], acc[i][j], 0, 0, 0);
    __syncthreads();
  }

  // epilogue: D col = lane&15, row = (lane>>4)*4 + reg   [m89 verified layout]
  #pragma unroll
  for (int i = 0; i < 4; ++i)
    #pragma unroll
    for (int j = 0; j < 4; ++j)
      #pragma unroll
      for (int r = 0; r < 4; ++r){
        int grow = m0 + wm*64 + i*16 + lq*4 + r;
        int gcol = n0 + wn*64 + j*16 + lr;
        float v = acc[i][j][r] + bias1[gcol];
        if (bias2) v += bias2[gcol];
        if constexpr (__is_same(TO, float)) C[(size_t)grow*N + gcol] = v;
        else                                C[(size_t)grow*N + gcol] = f2bf(v);
      }
}

extern "C" void kernel_launch(void* const* d_in, const int* in_sizes, int n_in,
                              void* d_out, int out_size, void* d_ws, size_t ws_size,
                              hipStream_t stream){
  (void)in_sizes; (void)n_in; (void)out_size; (void)ws_size;
  const float* x    = (const float*)d_in[0];
  const float* Wih  = (const float*)d_in[1];
  const float* Whh  = (const float*)d_in[2];
  const float* bih  = (const float*)d_in[3];
  const float* bhh  = (const float*)d_in[4];
  const float* Wout = (const float*)d_in[5];
  const float* bout = (const float*)d_in[6];
  float* y     = (float*)d_out;
  float* hlast = y + (size_t)T_DIM * B_DIM * O_DIM;

  char* ws = (char*)d_ws;
  const size_t MB = 1024*1024;
  unsigned short* xp   = (unsigned short*)ws;                      // 32 MB
  unsigned short* rnn  = (unsigned short*)(ws + 32*MB);            // 32 MB
  int*            Wq   = (int*)           (ws + 64*MB);            // 256 KB
  unsigned short* wob  = (unsigned short*)(ws + 64*MB + 256*1024); // 256 KB
  unsigned short* wihb = (unsigned short*)(ws + 64*MB + 512*1024); // 256 KB

  // pack W_ih/W_out + quant W_hh: 2*32768 + 65536 = 131072 = 512*256
  pack_w<<<512, 256, 0, stream>>>(Wih, Wout, Whh, wihb, wob, Wq);
  gemm_bt128<float, unsigned short><<<dim3(4, 256), 256, 0, stream>>>(
      x, wihb, xp, bih, bhh, T_DIM*B_DIM, H_DIM, I_DIM);
  rnn_recur<<<64, 512, 0, stream>>>(Wq, xp, rnn, hlast);
  gemm_bt128<unsigned short, float><<<dim3(2, 256), 256, 0, stream>>>(
      rnn, wob, y, bout, nullptr, T_DIM*B_DIM, O_DIM, H_DIM);
}